// Round 1
// 196.718 us; speedup vs baseline: 1.0158x; 1.0158x over previous
//
#include <hip/hip_runtime.h>

// DeltaSynapse: I[b,o] = sum_{d,e} s_e*W[e,o]*delaymap[d,e,o]*Xd[d,b,e]*(1+Wshort[d,b,e])
// Xd is ~2% sparse: pass1 compacts nonzero (e, coef) per (d,b); pass2 accumulates
// c * W[e,:] * delaymap[d,e,:] into per-(d,part) partial slices (no atomics);
// pass3 reduces the 16 slices into I.
//
// v2 (this round): ESPLIT 4->2 (partial 4MB->2MB, inner loop 10->20 iters),
// LDS staging removed from accum (entry loads are wave-uniform -> scalar loads,
// no barriers), pass1/pass3 float4-vectorized.

constexpr int D = 8, B = 16, E = 2048, O = 2048;
constexpr int DB = D * B;
constexpr int OTILE = 512;            // o-columns per block
constexpr int THREADS2 = OTILE / 4;   // 128 threads, float4 per thread
constexpr int ESPLIT = 2;             // split entry list across blocks
constexpr int NSLICE = D * ESPLIT;    // 16 partial slices

struct Entry { int e; float c; };

// ---------------- Pass 1: build per-(d,b) compacted spike lists ----------------
__global__ __launch_bounds__(256) void build_lists(
    const float* __restrict__ Xd, const float* __restrict__ Wshort,
    const int* __restrict__ signs, int* __restrict__ counts,
    Entry* __restrict__ entries)
{
    const int db = blockIdx.x;              // db = d*B + b
    __shared__ int cnt;
    if (threadIdx.x == 0) cnt = 0;
    __syncthreads();
    const float4* __restrict__ xrow = (const float4*)(Xd + (size_t)db * E);
    const float4* __restrict__ wsr  = (const float4*)(Wshort + (size_t)db * E);
    Entry* __restrict__ out = entries + (size_t)db * E;
    for (int q = threadIdx.x; q < E / 4; q += 256) {
        float4 x = xrow[q];
        if (x.x == 0.f && x.y == 0.f && x.z == 0.f && x.w == 0.f) continue;
        float4 ws = wsr[q];
        const float xa[4] = {x.x, x.y, x.z, x.w};
        const float wa[4] = {ws.x, ws.y, ws.z, ws.w};
        #pragma unroll
        for (int k = 0; k < 4; ++k) {
            if (xa[k] != 0.f) {
                int e = q * 4 + k;
                float s = (float)(2 * signs[e] - 1);   // {0,1} -> {-1,+1}
                float c = xa[k] * s * (1.0f + wa[k]);
                int slot = atomicAdd(&cnt, 1);         // shared-mem atomic, order irrelevant
                out[slot].e = e;
                out[slot].c = c;
            }
        }
    }
    __syncthreads();
    if (threadIdx.x == 0) counts[db] = cnt;
}

// ---------------- Pass 2: accumulate into partial slices ----------------
__global__ __launch_bounds__(THREADS2) void accum(
    const float* __restrict__ W, const float* __restrict__ dm,
    const int* __restrict__ counts, const Entry* __restrict__ entries,
    float* __restrict__ partial)
{
    const int tile = blockIdx.x;            // 0 .. O/OTILE-1
    const int part = blockIdx.y;            // 0 .. ESPLIT-1
    const int db   = blockIdx.z;            // 0 .. DB-1
    const int d = db >> 4;                  // db / B
    const int b = db & 15;                  // db % B
    const int o0 = tile * OTILE + (int)threadIdx.x * 4;

    const int n = counts[db];
    // Entry index stream part, part+ESPLIT, ... : wave-uniform addresses ->
    // scalar loads, no LDS staging / barriers needed.
    const Entry* __restrict__ lst = entries + (size_t)db * E + part;
    const int m = (n > part) ? ((n - part + ESPLIT - 1) / ESPLIT) : 0;

    const float* __restrict__ Wt  = W  + o0;
    const float* __restrict__ dmd = dm + (size_t)d * E * O + o0;
    float4 acc = make_float4(0.f, 0.f, 0.f, 0.f);
    #pragma unroll 4
    for (int j = 0; j < m; ++j) {
        Entry en = lst[j * ESPLIT];
        const float4 w  = *(const float4*)(Wt  + (size_t)en.e * O);
        const float4 mm = *(const float4*)(dmd + (size_t)en.e * O);
        acc.x += en.c * w.x * mm.x;
        acc.y += en.c * w.y * mm.y;
        acc.z += en.c * w.z * mm.z;
        acc.w += en.c * w.w * mm.w;
    }

    // Unconditional full-coverage write -> no pre-zeroing needed.
    float* p = partial + ((size_t)(d * ESPLIT + part) * B + b) * O + o0;
    *(float4*)p = acc;
}

// ---------------- Pass 3: reduce 16 slices -> I ----------------
__global__ __launch_bounds__(256) void reduce_slices(
    const float* __restrict__ partial, float* __restrict__ Iout)
{
    const int q = blockIdx.x * 256 + threadIdx.x;   // float4 index, 0 .. B*O/4-1
    const float4* __restrict__ p = (const float4*)partial;
    float4 s = make_float4(0.f, 0.f, 0.f, 0.f);
    #pragma unroll
    for (int k = 0; k < NSLICE; ++k) {
        float4 v = p[(size_t)k * (B * O / 4) + q];
        s.x += v.x; s.y += v.y; s.z += v.z; s.w += v.w;
    }
    ((float4*)Iout)[q] = s;
}

extern "C" void kernel_launch(void* const* d_in, const int* in_sizes, int n_in,
                              void* d_out, int out_size, void* d_ws, size_t ws_size,
                              hipStream_t stream) {
    const float* W     = (const float*)d_in[0];   // (E, O)
    const float* Xd    = (const float*)d_in[1];   // (D, B, E)
    const float* dm    = (const float*)d_in[2];   // (D, E, O)
    const float* Wsh   = (const float*)d_in[3];   // (D, B, E)
    const int*   signs = (const int*)d_in[4];     // (E,)
    float* Iout = (float*)d_out;                  // (B, O) fp32

    // workspace layout:
    //   [0, 512)            counts[DB]
    //   [512, 512+2MB)      entries[DB][E]
    //   [4MB, 6MB)          partial[NSLICE][B][O]
    int*   counts  = (int*)d_ws;
    Entry* entries = (Entry*)((char*)d_ws + 512);
    float* partial = (float*)((char*)d_ws + (4u << 20));

    build_lists<<<dim3(DB), dim3(256), 0, stream>>>(Xd, Wsh, signs, counts, entries);
    dim3 grid(O / OTILE, ESPLIT, DB);
    accum<<<grid, dim3(THREADS2), 0, stream>>>(W, dm, counts, entries, partial);
    reduce_slices<<<dim3(B * O / (256 * 4)), dim3(256), 0, stream>>>(partial, Iout);
}

// Round 2
// 193.713 us; speedup vs baseline: 1.0315x; 1.0155x over previous
//
#include <hip/hip_runtime.h>

// DeltaSynapse: I[b,o] = sum_{d,e} s_e*W[e,o]*delaymap[d,e,o]*Xd[d,b,e]*(1+Wshort[d,b,e])
// Xd is ~2% sparse: pass1 compacts nonzero (e, coef) per (d,b,part) where part
// partitions the e-range into ESPLIT contiguous chunks (own count, own sub-list
// -> unit-stride entry reads in pass2); pass2 accumulates c * W[e,:] * dm[d,e,:]
// into per-(d,part) partial slices (no atomics); pass3 reduces 32 slices into I.
//
// v3: ESPLIT 2->4 with e-space partitioning in pass1 (contiguous sub-lists,
// 512 build blocks, 2048 accum blocks = 16 waves/CU), reduce re-gridded to
// 128 blocks.

constexpr int D = 8, B = 16, E = 2048, O = 2048;
constexpr int DB = D * B;
constexpr int OTILE = 512;            // o-columns per accum block
constexpr int THREADS2 = OTILE / 4;   // 128 threads, float4 per thread
constexpr int ESPLIT = 4;             // e-range chunks (and slice split)
constexpr int ECHUNK = E / ESPLIT;    // 512 e's per chunk
constexpr int NSLICE = D * ESPLIT;    // 32 partial slices

struct Entry { int e; float c; };

// ---------------- Pass 1: per-(d,b,part) compacted spike sub-lists ----------------
__global__ __launch_bounds__(128) void build_lists(
    const float* __restrict__ Xd, const float* __restrict__ Wshort,
    const int* __restrict__ signs, int* __restrict__ counts,
    Entry* __restrict__ entries)
{
    const int db   = blockIdx.x;            // d*B + b
    const int part = blockIdx.y;            // e-chunk
    const int e0   = part * ECHUNK;
    __shared__ int cnt;
    if (threadIdx.x == 0) cnt = 0;
    __syncthreads();
    const float4* __restrict__ xrow = (const float4*)(Xd + (size_t)db * E + e0);
    const float4* __restrict__ wsr  = (const float4*)(Wshort + (size_t)db * E + e0);
    Entry* __restrict__ out = entries + (size_t)db * E + e0;
    // ECHUNK/4 = 128 float4s, one per thread
    const int q = threadIdx.x;
    float4 x = xrow[q];
    if (x.x != 0.f || x.y != 0.f || x.z != 0.f || x.w != 0.f) {
        float4 ws = wsr[q];
        const float xa[4] = {x.x, x.y, x.z, x.w};
        const float wa[4] = {ws.x, ws.y, ws.z, ws.w};
        #pragma unroll
        for (int k = 0; k < 4; ++k) {
            if (xa[k] != 0.f) {
                int e = e0 + q * 4 + k;
                float s = (float)(2 * signs[e] - 1);   // {0,1} -> {-1,+1}
                float c = xa[k] * s * (1.0f + wa[k]);
                int slot = atomicAdd(&cnt, 1);         // shared-mem atomic, order irrelevant
                out[slot].e = e;
                out[slot].c = c;
            }
        }
    }
    __syncthreads();
    if (threadIdx.x == 0) counts[db * ESPLIT + part] = cnt;
}

// ---------------- Pass 2: accumulate into partial slices ----------------
__global__ __launch_bounds__(THREADS2) void accum(
    const float* __restrict__ W, const float* __restrict__ dm,
    const int* __restrict__ counts, const Entry* __restrict__ entries,
    float* __restrict__ partial)
{
    const int tile = blockIdx.x;            // 0 .. O/OTILE-1
    const int part = blockIdx.y;            // 0 .. ESPLIT-1
    const int db   = blockIdx.z;            // 0 .. DB-1
    const int d = db >> 4;                  // db / B
    const int b = db & 15;                  // db % B
    const int o0 = tile * OTILE + (int)threadIdx.x * 4;

    const int m = counts[db * ESPLIT + part];
    // Contiguous sub-list for this e-chunk: unit-stride wave-uniform loads.
    const Entry* __restrict__ lst = entries + (size_t)db * E + part * ECHUNK;

    const float* __restrict__ Wt  = W  + o0;
    const float* __restrict__ dmd = dm + (size_t)d * E * O + o0;
    float4 acc = make_float4(0.f, 0.f, 0.f, 0.f);
    #pragma unroll 4
    for (int j = 0; j < m; ++j) {
        Entry en = lst[j];
        const float4 w  = *(const float4*)(Wt  + (size_t)en.e * O);
        const float4 mm = *(const float4*)(dmd + (size_t)en.e * O);
        acc.x += en.c * w.x * mm.x;
        acc.y += en.c * w.y * mm.y;
        acc.z += en.c * w.z * mm.z;
        acc.w += en.c * w.w * mm.w;
    }

    // Unconditional full-coverage write -> no pre-zeroing needed.
    float* p = partial + ((size_t)(d * ESPLIT + part) * B + b) * O + o0;
    *(float4*)p = acc;
}

// ---------------- Pass 3: reduce 32 slices -> I ----------------
__global__ __launch_bounds__(128) void reduce_slices(
    const float* __restrict__ partial, float* __restrict__ Iout)
{
    const int q = blockIdx.x * 128 + threadIdx.x;   // float2 index, 0 .. B*O/2-1
    const float2* __restrict__ p = (const float2*)partial;
    float2 s = make_float2(0.f, 0.f);
    #pragma unroll
    for (int k = 0; k < NSLICE; ++k) {
        float2 v = p[(size_t)k * (B * O / 2) + q];
        s.x += v.x; s.y += v.y;
    }
    ((float2*)Iout)[q] = s;
}

extern "C" void kernel_launch(void* const* d_in, const int* in_sizes, int n_in,
                              void* d_out, int out_size, void* d_ws, size_t ws_size,
                              hipStream_t stream) {
    const float* W     = (const float*)d_in[0];   // (E, O)
    const float* Xd    = (const float*)d_in[1];   // (D, B, E)
    const float* dm    = (const float*)d_in[2];   // (D, E, O)
    const float* Wsh   = (const float*)d_in[3];   // (D, B, E)
    const int*   signs = (const int*)d_in[4];     // (E,)
    float* Iout = (float*)d_out;                  // (B, O) fp32

    // workspace layout:
    //   [0, 4K)             counts[DB*ESPLIT]   (2 KB used)
    //   [4K, 4K+2MB)        entries[DB][E]
    //   [4MB, 8MB)          partial[NSLICE][B][O]
    int*   counts  = (int*)d_ws;
    Entry* entries = (Entry*)((char*)d_ws + 4096);
    float* partial = (float*)((char*)d_ws + (4u << 20));

    build_lists<<<dim3(DB, ESPLIT), dim3(128), 0, stream>>>(Xd, Wsh, signs, counts, entries);
    dim3 grid(O / OTILE, ESPLIT, DB);
    accum<<<grid, dim3(THREADS2), 0, stream>>>(W, dm, counts, entries, partial);
    reduce_slices<<<dim3(B * O / (128 * 2)), dim3(128), 0, stream>>>(partial, Iout);
}

// Round 3
// 191.145 us; speedup vs baseline: 1.0454x; 1.0134x over previous
//
#include <hip/hip_runtime.h>

// DeltaSynapse: I[b,o] = sum_{d,e} s_e*W[e,o]*delaymap[d,e,o]*Xd[d,b,e]*(1+Wshort[d,b,e])
// Xd is ~2% sparse. v4: pass1 fused into accum — each block owns one
// (e-chunk, d, b); it scans its 2KB Xd/Wshort chunk, compacts nonzero
// (e, coef) into LDS, then accumulates c * W[e,:] * dm[d,e,:] over the full
// o-range into its private partial slice (no atomics). Pass B reduces the
// 32 slices into I. Two kernels total.

constexpr int D = 8, B = 16, E = 2048, O = 2048;
constexpr int DB = D * B;
constexpr int ESPLIT = 4;             // e-range chunks (and slice split)
constexpr int ECHUNK = E / ESPLIT;    // 512 e's per chunk
constexpr int NSLICE = D * ESPLIT;    // 32 partial slices
constexpr int THREADS2 = 512;         // one thread per 4 o-columns (O/4)

struct Entry { int e; float c; };

// ---------------- Pass A: fused scan+compact+accumulate ----------------
__global__ __launch_bounds__(THREADS2) void accum_fused(
    const float* __restrict__ W, const float* __restrict__ dm,
    const float* __restrict__ Xd, const float* __restrict__ Wshort,
    const int* __restrict__ signs, float* __restrict__ partial)
{
    const int part = blockIdx.x;            // 0 .. ESPLIT-1
    const int db   = blockIdx.y;            // 0 .. DB-1
    const int d = db >> 4;                  // db / B
    const int b = db & 15;                  // db % B
    const int e0 = part * ECHUNK;

    __shared__ int cnt;
    __shared__ Entry sh[ECHUNK];            // 4 KB
    if (threadIdx.x == 0) cnt = 0;
    __syncthreads();

    // Scan this (db, chunk): 128 float4s, threads 0..127.
    if (threadIdx.x < ECHUNK / 4) {
        const int q = threadIdx.x;
        float4 x = ((const float4*)(Xd + (size_t)db * E + e0))[q];
        if (x.x != 0.f || x.y != 0.f || x.z != 0.f || x.w != 0.f) {
            float4 ws = ((const float4*)(Wshort + (size_t)db * E + e0))[q];
            int4   sg = ((const int4*)(signs + e0))[q];
            const float xa[4] = {x.x, x.y, x.z, x.w};
            const float wa[4] = {ws.x, ws.y, ws.z, ws.w};
            const int   sa[4] = {sg.x, sg.y, sg.z, sg.w};
            #pragma unroll
            for (int k = 0; k < 4; ++k) {
                if (xa[k] != 0.f) {
                    float s = (float)(2 * sa[k] - 1);     // {0,1} -> {-1,+1}
                    float c = xa[k] * s * (1.0f + wa[k]);
                    int slot = atomicAdd(&cnt, 1);        // LDS atomic, order irrelevant
                    sh[slot].e = e0 + q * 4 + k;
                    sh[slot].c = c;
                }
            }
        }
    }
    __syncthreads();
    const int m = cnt;

    const int o0 = (int)threadIdx.x * 4;
    const float* __restrict__ Wt  = W  + o0;
    const float* __restrict__ dmd = dm + (size_t)d * E * O + o0;
    float4 acc = make_float4(0.f, 0.f, 0.f, 0.f);
    #pragma unroll 4
    for (int j = 0; j < m; ++j) {
        Entry en = sh[j];                   // uniform address -> LDS broadcast
        const float4 w  = *(const float4*)(Wt  + (size_t)en.e * O);
        const float4 mm = *(const float4*)(dmd + (size_t)en.e * O);
        acc.x += en.c * w.x * mm.x;
        acc.y += en.c * w.y * mm.y;
        acc.z += en.c * w.z * mm.z;
        acc.w += en.c * w.w * mm.w;
    }

    // Unconditional full-coverage write -> no pre-zeroing needed.
    float* p = partial + ((size_t)(d * ESPLIT + part) * B + b) * O + o0;
    *(float4*)p = acc;
}

// ---------------- Pass B: reduce 32 slices -> I ----------------
__global__ __launch_bounds__(128) void reduce_slices(
    const float* __restrict__ partial, float* __restrict__ Iout)
{
    const int q = blockIdx.x * 128 + threadIdx.x;   // float2 index, 0 .. B*O/2-1
    const float2* __restrict__ p = (const float2*)partial;
    float2 s = make_float2(0.f, 0.f);
    #pragma unroll
    for (int k = 0; k < NSLICE; ++k) {
        float2 v = p[(size_t)k * (B * O / 2) + q];
        s.x += v.x; s.y += v.y;
    }
    ((float2*)Iout)[q] = s;
}

extern "C" void kernel_launch(void* const* d_in, const int* in_sizes, int n_in,
                              void* d_out, int out_size, void* d_ws, size_t ws_size,
                              hipStream_t stream) {
    const float* W     = (const float*)d_in[0];   // (E, O)
    const float* Xd    = (const float*)d_in[1];   // (D, B, E)
    const float* dm    = (const float*)d_in[2];   // (D, E, O)
    const float* Wsh   = (const float*)d_in[3];   // (D, B, E)
    const int*   signs = (const int*)d_in[4];     // (E,)
    float* Iout = (float*)d_out;                  // (B, O) fp32

    // workspace layout: [0, 4MB) partial[NSLICE][B][O]
    float* partial = (float*)d_ws;

    accum_fused<<<dim3(ESPLIT, DB), dim3(THREADS2), 0, stream>>>(
        W, dm, Xd, Wsh, signs, partial);
    reduce_slices<<<dim3(B * O / (128 * 2)), dim3(128), 0, stream>>>(partial, Iout);
}